// Round 8
// baseline (307.473 us; speedup 1.0000x reference)
//
#include <hip/hip_runtime.h>
#include <stdint.h>

// StandardAttention: B=16, N=1024, DIM=768, H=12, Dh=64, SCALE=0.125
// fused cvt(x,w_qkv,w_proj) -> gemm_qkv (proven 128^2 m97-structure, 3 blocks/CU)
// -> flash_attn (S^T form, 2^x, no online max; in-register P; Q=32 rows/wave;
//    XCD-swizzled 1D grid; K via LDS, V DIRECT from L2) -> gemm_proj (+bias fp32).
// NOTE r1/r2: 256^2 8-phase rewrite = 137us vs 87us (grid quantization). Dead end.
// NOTE r4: P never touches LDS: sigma(n)=((n>>2)&3)*8+((n>>4)&1)*4+(n&3) permutes
// P-cols and V-rows identically (key axis is private); lane's packed S^T regs
// ARE the PV A-fragment. V^T written sigma-permuted in gemm_qkv.
// NOTE r5/r6 FAILURE: Q=64 rows/wave spills (WRITE_SIZE 425/160MB vs 25MB algo).
// Q=32/wave fits with headroom. Do not raise rows/wave again.
// NOTE r6 WIN (kept): XCD-bijective swizzle. bid -> bh=x+8c, qt: all 8 q-tiles
// of one bh congruent mod 8 -> same XCD L2 (12 bh x 256KB = 3MB < 4MB).
// Flash FETCH measured at compulsory minimum (76.5MB).
// NOTE r8: all 4 waves read IDENTICAL K/V frags from LDS (4x redundancy, ~25us
// of LDS-port time vs ~7us MFMA). V now read per-wave DIRECT from global
// (L2-resident by the swizzle); loads issued at iter top, consumed in PV ->
// QK+exp2 phase hides L2 latency. LDS traffic halved, Vs buffer freed.

typedef unsigned short u16;
typedef __attribute__((ext_vector_type(8))) short s16x8;   // 8 x bf16 MFMA frag
typedef __attribute__((ext_vector_type(4))) float f32x4;   // MFMA accum
typedef __attribute__((ext_vector_type(4))) unsigned short u16x4;

#define SEQ 1024
#define NHEAD 12
#define HD 64

__device__ __forceinline__ u16 f2bf(float f) {
  union { float f; uint32_t u; } v; v.f = f;
  uint32_t u = v.u;
  return (u16)((u + 0x7FFFu + ((u >> 16) & 1u)) >> 16);   // RNE
}

__device__ __forceinline__ float exp2_fast(float x) {
  return __builtin_amdgcn_exp2f(x);
}

__device__ __forceinline__ uint32_t pk_bf16(float a, float b) {
#if __has_builtin(__builtin_amdgcn_cvt_pk_bf16_f32)
  typedef __attribute__((ext_vector_type(2))) __bf16 bf2;
  union { bf2 v; uint32_t u; } c;
  c.v = __builtin_amdgcn_cvt_pk_bf16_f32(a, b);
  return c.u;
#else
  union { float f; uint32_t u; } ua, ub; ua.f = a; ub.f = b;
  const uint32_t ra = ua.u + 0x8000u, rb = ub.u + 0x8000u;
  return __builtin_amdgcn_perm(ra, rb, 0x03020706u);
#endif
}

__device__ __forceinline__ void gld_lds16(const void* g, void* l) {
  __builtin_amdgcn_global_load_lds((const __attribute__((address_space(1))) void*)g,
                                   (__attribute__((address_space(3))) void*)l, 16, 0, 0);
}

// One launch converts x, w_qkv, w_proj (3 disjoint fp32 sources -> contiguous
// bf16 workspace regions). Block-range select; branches are wave-uniform
// except at the two boundaries.
__global__ void cvt_bf16_3(const float* __restrict__ in0, u16* __restrict__ out0, int n0,
                           const float* __restrict__ in1, u16* __restrict__ out1, int n1,
                           const float* __restrict__ in2, u16* __restrict__ out2, int n2) {
  int i = blockIdx.x * blockDim.x + threadIdx.x;
  const float* in; u16* out;
  if (i < n0)            { in = in0; out = out0; }
  else if (i < n0 + n1)  { in = in1; out = out1; i -= n0; }
  else if (i < n0 + n1 + n2) { in = in2; out = out2; i -= n0 + n1; }
  else return;
  float4 f = ((const float4*)in)[i];
  u16x4 o;
  o.x = f2bf(f.x); o.y = f2bf(f.y); o.z = f2bf(f.z); o.w = f2bf(f.w);
  ((u16x4*)out)[i] = o;
}

// C = A[M,768] @ B^T, B row-major [N,768]. 128x128 tile, BK=64, 3 blocks/CU.
// EPI=0: scatter q(*0.125*log2e)/k to [B,H,N,64], V TRANSPOSED+sigma-permuted
//        to [B,H,64,N'] (N' = key-permuted column order for flash's in-reg P).
// EPI=1: +bias, fp32 out.
template <int EPI>
__global__ __launch_bounds__(256, 3)
void gemm_bt(const u16* __restrict__ A, const u16* __restrict__ B,
             u16* __restrict__ q, u16* __restrict__ k, u16* __restrict__ v,
             float* __restrict__ out, const float* __restrict__ bias) {
  __shared__ u16 As[128 * 64];
  __shared__ u16 Bs[128 * 64];
  const int tid = threadIdx.x;
  const int wv = tid >> 6, lane = tid & 63;
  const int quad = lane >> 4, l16 = lane & 15;
  const int m0 = blockIdx.x * 128, n0 = blockIdx.y * 128;
  const int wm = (wv & 1) * 64, wn = (wv >> 1) * 64;

  f32x4 acc[4][4];
#pragma unroll
  for (int i = 0; i < 4; i++)
#pragma unroll
    for (int j = 0; j < 4; j++) { acc[i][j].x = 0.f; acc[i][j].y = 0.f; acc[i][j].z = 0.f; acc[i][j].w = 0.f; }

  const int srow = (lane >> 3);
  const int scp = lane & 7;

  for (int kt = 0; kt < 768; kt += 64) {
    __syncthreads();
#pragma unroll
    for (int i = 0; i < 4; i++) {
      const int t = wv * 4 + i;
      const int row = t * 8 + srow;
      const int c = scp ^ (row & 7);
      gld_lds16(A + (size_t)(m0 + row) * 768 + kt + c * 8, &As[t * 512]);
      gld_lds16(B + (size_t)(n0 + row) * 768 + kt + c * 8, &Bs[t * 512]);
    }
    __syncthreads();
#pragma unroll
    for (int ks = 0; ks < 2; ks++) {
      s16x8 af[4], bf[4];
#pragma unroll
      for (int mi = 0; mi < 4; mi++) {
        const int ra = wm + mi * 16 + l16;
        const int ca = ((ks * 4 + quad) ^ (ra & 7)) * 8;
        af[mi] = *(const s16x8*)&As[ra * 64 + ca];
        const int rb = wn + mi * 16 + l16;
        const int cb = ((ks * 4 + quad) ^ (rb & 7)) * 8;
        bf[mi] = *(const s16x8*)&Bs[rb * 64 + cb];
      }
#pragma unroll
      for (int mi = 0; mi < 4; mi++)
#pragma unroll
        for (int ni = 0; ni < 4; ni++)
          acc[mi][ni] = __builtin_amdgcn_mfma_f32_16x16x32_bf16(af[mi], bf[ni], acc[mi][ni], 0, 0, 0);
    }
  }

  if (EPI == 0) {
#pragma unroll
    for (int ni = 0; ni < 4; ni++) {
      const int n = n0 + wn + ni * 16 + l16;
      const int which = n / 768;          // uniform per block (n-range within one third)
      const int rc = n % 768;
      const int head = rc >> 6, d = rc & 63;
      if (which == 2) {
        // V: transposed + sigma-permuted columns; r=0..3 stay contiguous -> 8B store
#pragma unroll
        for (int mi = 0; mi < 4; mi++) {
          const int mb = m0 + wm + mi * 16 + quad * 4;   // 4-aligned, same 1024-group for r=0..3
          const int b = mb >> 10, rrb = mb & 1023;
          const int vcol = (rrb & ~31) | (((rrb >> 2) & 3) << 3) | (((rrb >> 4) & 1) << 2);
          u16x4 pk4;
          pk4.x = f2bf(acc[mi][ni][0]); pk4.y = f2bf(acc[mi][ni][1]);
          pk4.z = f2bf(acc[mi][ni][2]); pk4.w = f2bf(acc[mi][ni][3]);
          *(u16x4*)&v[((size_t)(b * NHEAD + head) * HD + d) * SEQ + vcol] = pk4;
        }
      } else {
#pragma unroll
        for (int mi = 0; mi < 4; mi++) {
#pragma unroll
          for (int r = 0; r < 4; r++) {
            const int m = m0 + wm + mi * 16 + quad * 4 + r;
            const int b = m >> 10, rr = m & 1023;
            const float val = acc[mi][ni][r];
            if (which == 0)   // fold SCALE * log2(e) so flash uses 2^x directly
              q[((size_t)(b * NHEAD + head) * SEQ + rr) * HD + d] = f2bf(val * 0.18033688011112042f);
            else
              k[((size_t)(b * NHEAD + head) * SEQ + rr) * HD + d] = f2bf(val);
          }
        }
      }
    }
  } else {
#pragma unroll
    for (int mi = 0; mi < 4; mi++)
#pragma unroll
      for (int ni = 0; ni < 4; ni++)
#pragma unroll
        for (int r = 0; r < 4; r++) {
          const int m = m0 + wm + mi * 16 + quad * 4 + r;
          const int n = n0 + wn + ni * 16 + l16;
          out[(size_t)m * 768 + n] = acc[mi][ni][r] + bias[n];
        }
  }
}

// Flash attention, S^T form, no online max, 2^x. K double-buffered in LDS;
// V read DIRECT from global per wave (L2-resident via XCD swizzle), loads
// issued at iter top so QK+exp2 hides L2 latency. In-register P (r4 sigma
// trick). l via MFMA-ones. Q=32 rows/wave.
__global__ __launch_bounds__(256, 3)
void flash_attn(const u16* __restrict__ Q, const u16* __restrict__ K,
                const u16* __restrict__ VT, u16* __restrict__ O) {
  __shared__ u16 Ks[2][64 * 64];        // [key][d], chunks swizzled by key&7

  const int tid = threadIdx.x;
  const int wv = tid >> 6, lane = tid & 63;
  const int quad = lane >> 4, l16 = lane & 15;
  // bid = 64c + 8q + x  ->  bh = x + 8c (0..191), qtile = q (0..7).
  // Same-bh blocks congruent mod 8 -> same XCD under round-robin dispatch.
  const int bid = blockIdx.x;
  const int bh = (bid & 7) + 8 * (bid >> 6);
  const int qt = (bid >> 3) & 7;
  const int q0 = qt * 128 + wv * 32;
  const size_t base = (size_t)bh * SEQ * HD;
  const size_t vbase = (size_t)bh * HD * SEQ;

  const int sr0 = tid >> 3;
  const int sc0 = (tid & 7) ^ (sr0 & 7);
  const int sr1 = 32 + sr0;
  const int sc1 = (tid & 7) ^ (sr1 & 7);

  s16x8 qf[2][2];
#pragma unroll
  for (int g = 0; g < 2; g++)
#pragma unroll
    for (int ks = 0; ks < 2; ks++)
      qf[g][ks] = *(const s16x8*)(Q + base + (size_t)(q0 + g * 16 + l16) * HD + ks * 32 + quad * 8);

  const s16x8 ones = {0x3F80, 0x3F80, 0x3F80, 0x3F80, 0x3F80, 0x3F80, 0x3F80, 0x3F80};

  f32x4 acc[2][4], acc_l[2];
#pragma unroll
  for (int g = 0; g < 2; g++) {
    acc_l[g].x = 0.f; acc_l[g].y = 0.f; acc_l[g].z = 0.f; acc_l[g].w = 0.f;
#pragma unroll
    for (int t = 0; t < 4; t++) { acc[g][t].x = 0.f; acc[g][t].y = 0.f; acc[g][t].z = 0.f; acc[g][t].w = 0.f; }
  }

  const int swz = l16 & 7;

  // V-fragment base for this lane: row (t2*16+l16) of VT, key-slot (ks2*4+quad)*8.
  // (No LDS swizzle needed on the direct path.)
  const u16* vlane = VT + vbase + (size_t)l16 * SEQ + quad * 8;

  gld_lds16(K + base + (size_t)sr0 * HD + sc0 * 8, &Ks[0][wv * 512]);
  gld_lds16(K + base + (size_t)sr1 * HD + sc1 * 8, &Ks[0][2048 + wv * 512]);

  for (int it = 0; it < 16; it++) {
    __syncthreads();
    if (it + 1 < 16) {
      const int n1 = (it + 1) * 64;
      const int nb = (it + 1) & 1;
      gld_lds16(K + base + (size_t)(n1 + sr0) * HD + sc0 * 8, &Ks[nb][wv * 512]);
      gld_lds16(K + base + (size_t)(n1 + sr1) * HD + sc1 * 8, &Ks[nb][2048 + wv * 512]);
    }
    // Issue THIS iter's V loads now; consumed in PV after QK+exp2 (~400cy cover).
    s16x8 vv[2][4];
#pragma unroll
    for (int ks2 = 0; ks2 < 2; ks2++)
#pragma unroll
      for (int t2 = 0; t2 < 4; t2++)
        vv[ks2][t2] = *(const s16x8*)(vlane + (size_t)(t2 * 16) * SEQ + it * 64 + ks2 * 32);

    const u16* __restrict__ ks = Ks[it & 1];

    // S^T = K Q^T (q pre-scaled by 0.125*log2e)
    f32x4 s0[4], s1[4];
    __builtin_amdgcn_s_setprio(1);
#pragma unroll
    for (int t = 0; t < 4; t++) {
      s0[t].x = 0.f; s0[t].y = 0.f; s0[t].z = 0.f; s0[t].w = 0.f;
      s1[t].x = 0.f; s1[t].y = 0.f; s1[t].z = 0.f; s1[t].w = 0.f;
      const u16* kr = &ks[(t * 16 + l16) * 64];
      const s16x8 kf0 = *(const s16x8*)&kr[(quad ^ swz) * 8];
      const s16x8 kf1 = *(const s16x8*)&kr[((4 + quad) ^ swz) * 8];
      s0[t] = __builtin_amdgcn_mfma_f32_16x16x32_bf16(kf0, qf[0][0], s0[t], 0, 0, 0);
      s0[t] = __builtin_amdgcn_mfma_f32_16x16x32_bf16(kf1, qf[0][1], s0[t], 0, 0, 0);
      s1[t] = __builtin_amdgcn_mfma_f32_16x16x32_bf16(kf0, qf[1][0], s1[t], 0, 0, 0);
      s1[t] = __builtin_amdgcn_mfma_f32_16x16x32_bf16(kf1, qf[1][1], s1[t], 0, 0, 0);
    }
    __builtin_amdgcn_s_setprio(0);

    // p = 2^s
#pragma unroll
    for (int t = 0; t < 4; t++)
#pragma unroll
      for (int r = 0; r < 4; r++) {
        s0[t][r] = exp2_fast(s0[t][r]);
        s1[t][r] = exp2_fast(s1[t][r]);
      }

    // O += P V ; l += P @ ones. A-frags built in-register: slot quad*8+j holds
    // key 32*ks2 + quad*4 + 16*(j>>2) + (j&3) = exactly s[2*ks2 + (j>>2)][j&3];
    // sigma-permuted VT columns supply the matching keys.
    __builtin_amdgcn_s_setprio(1);
#pragma unroll
    for (int ks2 = 0; ks2 < 2; ks2++) {
      union { uint32_t w[4]; s16x8 v; } pa0, pa1;
      pa0.w[0] = pk_bf16(s0[2 * ks2][0], s0[2 * ks2][1]);
      pa0.w[1] = pk_bf16(s0[2 * ks2][2], s0[2 * ks2][3]);
      pa0.w[2] = pk_bf16(s0[2 * ks2 + 1][0], s0[2 * ks2 + 1][1]);
      pa0.w[3] = pk_bf16(s0[2 * ks2 + 1][2], s0[2 * ks2 + 1][3]);
      pa1.w[0] = pk_bf16(s1[2 * ks2][0], s1[2 * ks2][1]);
      pa1.w[1] = pk_bf16(s1[2 * ks2][2], s1[2 * ks2][3]);
      pa1.w[2] = pk_bf16(s1[2 * ks2 + 1][0], s1[2 * ks2 + 1][1]);
      pa1.w[3] = pk_bf16(s1[2 * ks2 + 1][2], s1[2 * ks2 + 1][3]);
      acc_l[0] = __builtin_amdgcn_mfma_f32_16x16x32_bf16(pa0.v, ones, acc_l[0], 0, 0, 0);
      acc_l[1] = __builtin_amdgcn_mfma_f32_16x16x32_bf16(pa1.v, ones, acc_l[1], 0, 0, 0);
#pragma unroll
      for (int t2 = 0; t2 < 4; t2++) {
        acc[0][t2] = __builtin_amdgcn_mfma_f32_16x16x32_bf16(pa0.v, vv[ks2][t2], acc[0][t2], 0, 0, 0);
        acc[1][t2] = __builtin_amdgcn_mfma_f32_16x16x32_bf16(pa1.v, vv[ks2][t2], acc[1][t2], 0, 0, 0);
      }
    }
    __builtin_amdgcn_s_setprio(0);
  }

  // write attn_out bf16 [B, N, H*64]; acc_l rows coincide with acc rows
  const int b = bh / NHEAD, h = bh % NHEAD;
#pragma unroll
  for (int g = 0; g < 2; g++) {
#pragma unroll
    for (int r = 0; r < 4; r++) {
      const float li = 1.0f / acc_l[g][r];
      const int qrow = q0 + g * 16 + quad * 4 + r;
      u16* op = O + (size_t)(b * SEQ + qrow) * 768 + h * HD;
#pragma unroll
      for (int t2 = 0; t2 < 4; t2++)
        op[t2 * 16 + l16] = f2bf(acc[g][t2][r] * li);
    }
  }
}

extern "C" void kernel_launch(void* const* d_in, const int* in_sizes, int n_in,
                              void* d_out, int out_size, void* d_ws, size_t ws_size,
                              hipStream_t stream) {
  (void)in_sizes; (void)n_in; (void)out_size; (void)ws_size;
  const float* x      = (const float*)d_in[0];
  const float* w_qkv  = (const float*)d_in[1];
  const float* w_proj = (const float*)d_in[2];
  const float* b_proj = (const float*)d_in[3];

  const size_t SZ_X   = (size_t)16384 * 768;
  const size_t SZ_WQ  = (size_t)2304 * 768;
  const size_t SZ_WP  = (size_t)768 * 768;
  const size_t SZ_HED = (size_t)16 * NHEAD * SEQ * HD;

  u16* xb   = (u16*)d_ws;
  u16* wqb  = xb + SZ_X;
  u16* wpb  = wqb + SZ_WQ;
  u16* qb   = wpb + SZ_WP;
  u16* kb   = qb + SZ_HED;
  u16* vtb  = kb + SZ_HED;     // V transposed, sigma-permuted [bh][d][n']
  u16* attn = vtb + SZ_HED;

  const int n0 = (int)(SZ_X / 4), n1 = (int)(SZ_WQ / 4), n2 = (int)(SZ_WP / 4);
  const int nblk = (n0 + n1 + n2 + 255) / 256;
  cvt_bf16_3<<<nblk, 256, 0, stream>>>(x, xb, n0, w_qkv, wqb, n1, w_proj, wpb, n2);

  gemm_bt<0><<<dim3(128, 18), 256, 0, stream>>>(xb, wqb, qb, kb, vtb, nullptr, nullptr);
  flash_attn<<<1536, 256, 0, stream>>>(qb, kb, vtb, attn);
  gemm_bt<1><<<dim3(128, 6), 256, 0, stream>>>(attn, wpb, nullptr, nullptr, nullptr,
                                               (float*)d_out, b_proj);
}

// Round 9
// 263.011 us; speedup vs baseline: 1.1690x; 1.1690x over previous
//
#include <hip/hip_runtime.h>
#include <stdint.h>

// StandardAttention: B=16, N=1024, DIM=768, H=12, Dh=64, SCALE=0.125
// fused cvt(x,w_qkv,w_proj) -> gemm_qkv (proven 128^2 m97-structure, 3 blocks/CU)
// -> flash_attn (S^T form, 2^x, no online max; in-register P; Q=32 rows/wave;
//    XCD-swizzled 1D grid; VALU l-sum) -> gemm_proj (same structure, +bias fp32).
// NOTE r1/r2: 256^2 8-phase rewrite = 137us vs 87us (grid quantization). Dead end.
// NOTE r4: P never touches LDS: sigma(n)=((n>>2)&3)*8+((n>>4)&1)*4+(n&3) permutes
// P-cols and V-rows identically (key axis is private); lane's packed S^T regs
// ARE the PV A-fragment. V^T written sigma-permuted in gemm_qkv.
// NOTE r5/r6 FAILURE: Q=64 rows/wave spills (WRITE 425/160MB vs 25MB algo).
// Q=32/wave fits. Do not raise rows/wave again.
// NOTE r6 WIN (kept): XCD-bijective swizzle -> same-bh blocks same XCD L2;
// flash FETCH at compulsory minimum (76.5MB).
// NOTE r8 FAILURE: V direct-from-L2 (no LDS) = 111.6us vs ~64 (clean counters;
// per-lane scattered 64B segments + exposed L2 latency). V stays in LDS.
// NOTE r8 AUDIT: total - sum(kernels) ~= 90us in EVERY round, invariant to
// launch count (r0 5-launch vs r3 4-launch) -> fixed harness overhead, not
// per-launch. Kernel fusion is NOT a lever. All kernels at structure ceiling:
// cvt 14 (HBM roofline), qkv 68 (853TF), proj 26 (743TF + 10us fp32 write),
// flash ~64 (890TF effective).
// NOTE r9: l via VALU partials (validated r5/r6) instead of MFMA-ones:
// -2 MFMA/iter (-11% flash MFMA), +32 VALU adds, -8 VGPR.

typedef unsigned short u16;
typedef __attribute__((ext_vector_type(8))) short s16x8;   // 8 x bf16 MFMA frag
typedef __attribute__((ext_vector_type(4))) float f32x4;   // MFMA accum
typedef __attribute__((ext_vector_type(4))) unsigned short u16x4;

#define SEQ 1024
#define NHEAD 12
#define HD 64

__device__ __forceinline__ u16 f2bf(float f) {
  union { float f; uint32_t u; } v; v.f = f;
  uint32_t u = v.u;
  return (u16)((u + 0x7FFFu + ((u >> 16) & 1u)) >> 16);   // RNE
}

__device__ __forceinline__ float exp2_fast(float x) {
  return __builtin_amdgcn_exp2f(x);
}

__device__ __forceinline__ uint32_t pk_bf16(float a, float b) {
#if __has_builtin(__builtin_amdgcn_cvt_pk_bf16_f32)
  typedef __attribute__((ext_vector_type(2))) __bf16 bf2;
  union { bf2 v; uint32_t u; } c;
  c.v = __builtin_amdgcn_cvt_pk_bf16_f32(a, b);
  return c.u;
#else
  union { float f; uint32_t u; } ua, ub; ua.f = a; ub.f = b;
  const uint32_t ra = ua.u + 0x8000u, rb = ub.u + 0x8000u;
  return __builtin_amdgcn_perm(ra, rb, 0x03020706u);
#endif
}

__device__ __forceinline__ void gld_lds16(const void* g, void* l) {
  __builtin_amdgcn_global_load_lds((const __attribute__((address_space(1))) void*)g,
                                   (__attribute__((address_space(3))) void*)l, 16, 0, 0);
}

// One launch converts x, w_qkv, w_proj (3 disjoint fp32 sources -> contiguous
// bf16 workspace regions). Block-range select; branches are wave-uniform
// except at the two boundaries.
__global__ void cvt_bf16_3(const float* __restrict__ in0, u16* __restrict__ out0, int n0,
                           const float* __restrict__ in1, u16* __restrict__ out1, int n1,
                           const float* __restrict__ in2, u16* __restrict__ out2, int n2) {
  int i = blockIdx.x * blockDim.x + threadIdx.x;
  const float* in; u16* out;
  if (i < n0)            { in = in0; out = out0; }
  else if (i < n0 + n1)  { in = in1; out = out1; i -= n0; }
  else if (i < n0 + n1 + n2) { in = in2; out = out2; i -= n0 + n1; }
  else return;
  float4 f = ((const float4*)in)[i];
  u16x4 o;
  o.x = f2bf(f.x); o.y = f2bf(f.y); o.z = f2bf(f.z); o.w = f2bf(f.w);
  ((u16x4*)out)[i] = o;
}

// C = A[M,768] @ B^T, B row-major [N,768]. 128x128 tile, BK=64, 3 blocks/CU.
// EPI=0: scatter q(*0.125*log2e)/k to [B,H,N,64], V TRANSPOSED+sigma-permuted
//        to [B,H,64,N'] (N' = key-permuted column order for flash's in-reg P).
// EPI=1: +bias, fp32 out.
template <int EPI>
__global__ __launch_bounds__(256, 3)
void gemm_bt(const u16* __restrict__ A, const u16* __restrict__ B,
             u16* __restrict__ q, u16* __restrict__ k, u16* __restrict__ v,
             float* __restrict__ out, const float* __restrict__ bias) {
  __shared__ u16 As[128 * 64];
  __shared__ u16 Bs[128 * 64];
  const int tid = threadIdx.x;
  const int wv = tid >> 6, lane = tid & 63;
  const int quad = lane >> 4, l16 = lane & 15;
  const int m0 = blockIdx.x * 128, n0 = blockIdx.y * 128;
  const int wm = (wv & 1) * 64, wn = (wv >> 1) * 64;

  f32x4 acc[4][4];
#pragma unroll
  for (int i = 0; i < 4; i++)
#pragma unroll
    for (int j = 0; j < 4; j++) { acc[i][j].x = 0.f; acc[i][j].y = 0.f; acc[i][j].z = 0.f; acc[i][j].w = 0.f; }

  const int srow = (lane >> 3);
  const int scp = lane & 7;

  for (int kt = 0; kt < 768; kt += 64) {
    __syncthreads();
#pragma unroll
    for (int i = 0; i < 4; i++) {
      const int t = wv * 4 + i;
      const int row = t * 8 + srow;
      const int c = scp ^ (row & 7);
      gld_lds16(A + (size_t)(m0 + row) * 768 + kt + c * 8, &As[t * 512]);
      gld_lds16(B + (size_t)(n0 + row) * 768 + kt + c * 8, &Bs[t * 512]);
    }
    __syncthreads();
#pragma unroll
    for (int ks = 0; ks < 2; ks++) {
      s16x8 af[4], bf[4];
#pragma unroll
      for (int mi = 0; mi < 4; mi++) {
        const int ra = wm + mi * 16 + l16;
        const int ca = ((ks * 4 + quad) ^ (ra & 7)) * 8;
        af[mi] = *(const s16x8*)&As[ra * 64 + ca];
        const int rb = wn + mi * 16 + l16;
        const int cb = ((ks * 4 + quad) ^ (rb & 7)) * 8;
        bf[mi] = *(const s16x8*)&Bs[rb * 64 + cb];
      }
#pragma unroll
      for (int mi = 0; mi < 4; mi++)
#pragma unroll
        for (int ni = 0; ni < 4; ni++)
          acc[mi][ni] = __builtin_amdgcn_mfma_f32_16x16x32_bf16(af[mi], bf[ni], acc[mi][ni], 0, 0, 0);
    }
  }

  if (EPI == 0) {
#pragma unroll
    for (int ni = 0; ni < 4; ni++) {
      const int n = n0 + wn + ni * 16 + l16;
      const int which = n / 768;          // uniform per block (n-range within one third)
      const int rc = n % 768;
      const int head = rc >> 6, d = rc & 63;
      if (which == 2) {
        // V: transposed + sigma-permuted columns; r=0..3 stay contiguous -> 8B store
#pragma unroll
        for (int mi = 0; mi < 4; mi++) {
          const int mb = m0 + wm + mi * 16 + quad * 4;   // 4-aligned, same 1024-group for r=0..3
          const int b = mb >> 10, rrb = mb & 1023;
          const int vcol = (rrb & ~31) | (((rrb >> 2) & 3) << 3) | (((rrb >> 4) & 1) << 2);
          u16x4 pk4;
          pk4.x = f2bf(acc[mi][ni][0]); pk4.y = f2bf(acc[mi][ni][1]);
          pk4.z = f2bf(acc[mi][ni][2]); pk4.w = f2bf(acc[mi][ni][3]);
          *(u16x4*)&v[((size_t)(b * NHEAD + head) * HD + d) * SEQ + vcol] = pk4;
        }
      } else {
#pragma unroll
        for (int mi = 0; mi < 4; mi++) {
#pragma unroll
          for (int r = 0; r < 4; r++) {
            const int m = m0 + wm + mi * 16 + quad * 4 + r;
            const int b = m >> 10, rr = m & 1023;
            const float val = acc[mi][ni][r];
            if (which == 0)   // fold SCALE * log2(e) so flash uses 2^x directly
              q[((size_t)(b * NHEAD + head) * SEQ + rr) * HD + d] = f2bf(val * 0.18033688011112042f);
            else
              k[((size_t)(b * NHEAD + head) * SEQ + rr) * HD + d] = f2bf(val);
          }
        }
      }
    }
  } else {
#pragma unroll
    for (int mi = 0; mi < 4; mi++)
#pragma unroll
      for (int ni = 0; ni < 4; ni++)
#pragma unroll
        for (int r = 0; r < 4; r++) {
          const int m = m0 + wm + mi * 16 + quad * 4 + r;
          const int n = n0 + wn + ni * 16 + l16;
          out[(size_t)m * 768 + n] = acc[mi][ni][r] + bias[n];
        }
  }
}

// Flash attention, S^T form, no online max, 2^x, double-buffered K/V in LDS
// (r7-verified body). In-register P (r4 sigma trick). l via VALU partials +
// quad-butterfly + shfl epilogue (validated r5/r6). Q=32 rows/wave.
// Grid: 1D 1536 with XCD-bijective swizzle (same-bh blocks share an XCD L2).
__global__ __launch_bounds__(256, 3)
void flash_attn(const u16* __restrict__ Q, const u16* __restrict__ K,
                const u16* __restrict__ VT, u16* __restrict__ O) {
  __shared__ u16 Ks[2][64 * 64];        // [key][d], chunks swizzled by key&7
  __shared__ u16 Vs[2][64 * 64];        // [d][key'], chunks swizzled by d&7

  const int tid = threadIdx.x;
  const int wv = tid >> 6, lane = tid & 63;
  const int quad = lane >> 4, l16 = lane & 15;
  // bid = 64c + 8q + x  ->  bh = x + 8c (0..191), qtile = q (0..7).
  // Same-bh blocks congruent mod 8 -> same XCD under round-robin dispatch.
  const int bid = blockIdx.x;
  const int bh = (bid & 7) + 8 * (bid >> 6);
  const int qt = (bid >> 3) & 7;
  const int q0 = qt * 128 + wv * 32;
  const size_t base = (size_t)bh * SEQ * HD;
  const size_t vbase = (size_t)bh * HD * SEQ;

  const int sr0 = tid >> 3;
  const int sc0 = (tid & 7) ^ (sr0 & 7);
  const int sr1 = 32 + sr0;
  const int sc1 = (tid & 7) ^ (sr1 & 7);

  s16x8 qf[2][2];
#pragma unroll
  for (int g = 0; g < 2; g++)
#pragma unroll
    for (int ks = 0; ks < 2; ks++)
      qf[g][ks] = *(const s16x8*)(Q + base + (size_t)(q0 + g * 16 + l16) * HD + ks * 32 + quad * 8);

  f32x4 acc[2][4];
  float lp[2] = {0.f, 0.f};
#pragma unroll
  for (int g = 0; g < 2; g++)
#pragma unroll
    for (int t = 0; t < 4; t++) { acc[g][t].x = 0.f; acc[g][t].y = 0.f; acc[g][t].z = 0.f; acc[g][t].w = 0.f; }

  const int swz = l16 & 7;

  gld_lds16(K + base + (size_t)sr0 * HD + sc0 * 8, &Ks[0][wv * 512]);
  gld_lds16(VT + vbase + (size_t)sr0 * SEQ + sc0 * 8, &Vs[0][wv * 512]);
  gld_lds16(K + base + (size_t)sr1 * HD + sc1 * 8, &Ks[0][2048 + wv * 512]);
  gld_lds16(VT + vbase + (size_t)sr1 * SEQ + sc1 * 8, &Vs[0][2048 + wv * 512]);

  for (int it = 0; it < 16; it++) {
    __syncthreads();
    if (it + 1 < 16) {
      const int n1 = (it + 1) * 64;
      const int nb = (it + 1) & 1;
      gld_lds16(K + base + (size_t)(n1 + sr0) * HD + sc0 * 8, &Ks[nb][wv * 512]);
      gld_lds16(VT + vbase + (size_t)sr0 * SEQ + n1 + sc0 * 8, &Vs[nb][wv * 512]);
      gld_lds16(K + base + (size_t)(n1 + sr1) * HD + sc1 * 8, &Ks[nb][2048 + wv * 512]);
      gld_lds16(VT + vbase + (size_t)sr1 * SEQ + n1 + sc1 * 8, &Vs[nb][2048 + wv * 512]);
    }
    const u16* __restrict__ ks = Ks[it & 1];
    const u16* __restrict__ vs = Vs[it & 1];

    // S^T = K Q^T (q pre-scaled by 0.125*log2e)
    f32x4 s0[4], s1[4];
    __builtin_amdgcn_s_setprio(1);
#pragma unroll
    for (int t = 0; t < 4; t++) {
      s0[t].x = 0.f; s0[t].y = 0.f; s0[t].z = 0.f; s0[t].w = 0.f;
      s1[t].x = 0.f; s1[t].y = 0.f; s1[t].z = 0.f; s1[t].w = 0.f;
      const u16* kr = &ks[(t * 16 + l16) * 64];
      const s16x8 kf0 = *(const s16x8*)&kr[(quad ^ swz) * 8];
      const s16x8 kf1 = *(const s16x8*)&kr[((4 + quad) ^ swz) * 8];
      s0[t] = __builtin_amdgcn_mfma_f32_16x16x32_bf16(kf0, qf[0][0], s0[t], 0, 0, 0);
      s0[t] = __builtin_amdgcn_mfma_f32_16x16x32_bf16(kf1, qf[0][1], s0[t], 0, 0, 0);
      s1[t] = __builtin_amdgcn_mfma_f32_16x16x32_bf16(kf0, qf[1][0], s1[t], 0, 0, 0);
      s1[t] = __builtin_amdgcn_mfma_f32_16x16x32_bf16(kf1, qf[1][1], s1[t], 0, 0, 0);
    }
    __builtin_amdgcn_s_setprio(0);

    // p = 2^s ; accumulate l partials on the VALU (lane's quad-slice of keys)
#pragma unroll
    for (int t = 0; t < 4; t++) {
#pragma unroll
      for (int r = 0; r < 4; r++) {
        s0[t][r] = exp2_fast(s0[t][r]);
        s1[t][r] = exp2_fast(s1[t][r]);
      }
      lp[0] += (s0[t][0] + s0[t][1]) + (s0[t][2] + s0[t][3]);
      lp[1] += (s1[t][0] + s1[t][1]) + (s1[t][2] + s1[t][3]);
    }

    // O += P V. A-frags built in-register: slot quad*8+j holds key
    // 32*ks2 + quad*4 + 16*(j>>2) + (j&3) = exactly s[2*ks2 + (j>>2)][j&3];
    // sigma-permuted Vs columns supply the matching keys.
    __builtin_amdgcn_s_setprio(1);
#pragma unroll
    for (int ks2 = 0; ks2 < 2; ks2++) {
      union { uint32_t w[4]; s16x8 v; } pa0, pa1;
      pa0.w[0] = pk_bf16(s0[2 * ks2][0], s0[2 * ks2][1]);
      pa0.w[1] = pk_bf16(s0[2 * ks2][2], s0[2 * ks2][3]);
      pa0.w[2] = pk_bf16(s0[2 * ks2 + 1][0], s0[2 * ks2 + 1][1]);
      pa0.w[3] = pk_bf16(s0[2 * ks2 + 1][2], s0[2 * ks2 + 1][3]);
      pa1.w[0] = pk_bf16(s1[2 * ks2][0], s1[2 * ks2][1]);
      pa1.w[1] = pk_bf16(s1[2 * ks2][2], s1[2 * ks2][3]);
      pa1.w[2] = pk_bf16(s1[2 * ks2 + 1][0], s1[2 * ks2 + 1][1]);
      pa1.w[3] = pk_bf16(s1[2 * ks2 + 1][2], s1[2 * ks2 + 1][3]);
      const int cp = ((ks2 * 4 + quad) ^ swz) * 8;
#pragma unroll
      for (int t2 = 0; t2 < 4; t2++) {
        const s16x8 vf = *(const s16x8*)&vs[(t2 * 16 + l16) * 64 + cp];
        acc[0][t2] = __builtin_amdgcn_mfma_f32_16x16x32_bf16(pa0.v, vf, acc[0][t2], 0, 0, 0);
        acc[1][t2] = __builtin_amdgcn_mfma_f32_16x16x32_bf16(pa1.v, vf, acc[1][t2], 0, 0, 0);
      }
    }
    __builtin_amdgcn_s_setprio(0);
  }

  // l: lp[g] = sum over this lane's quad-slice for q=l16. Butterfly over
  // quads (xor 16, 32) -> lf = l[q=l16]; shfl lane quad*4+r supplies the l
  // for output row quad*4+r (C-layout). Validated r5/r6.
  const int b = bh / NHEAD, h = bh % NHEAD;
#pragma unroll
  for (int g = 0; g < 2; g++) {
    float lf = lp[g];
    lf += __shfl_xor(lf, 16);
    lf += __shfl_xor(lf, 32);
#pragma unroll
    for (int r = 0; r < 4; r++) {
      const float li = 1.0f / __shfl(lf, quad * 4 + r);
      const int qrow = q0 + g * 16 + quad * 4 + r;
      u16* op = O + (size_t)(b * SEQ + qrow) * 768 + h * HD;
#pragma unroll
      for (int t2 = 0; t2 < 4; t2++)
        op[t2 * 16 + l16] = f2bf(acc[g][t2][r] * li);
    }
  }
}

extern "C" void kernel_launch(void* const* d_in, const int* in_sizes, int n_in,
                              void* d_out, int out_size, void* d_ws, size_t ws_size,
                              hipStream_t stream) {
  (void)in_sizes; (void)n_in; (void)out_size; (void)ws_size;
  const float* x      = (const float*)d_in[0];
  const float* w_qkv  = (const float*)d_in[1];
  const float* w_proj = (const float*)d_in[2];
  const float* b_proj = (const float*)d_in[3];

  const size_t SZ_X   = (size_t)16384 * 768;
  const size_t SZ_WQ  = (size_t)2304 * 768;
  const size_t SZ_WP  = (size_t)768 * 768;
  const size_t SZ_HED = (size_t)16 * NHEAD * SEQ * HD;

  u16* xb   = (u16*)d_ws;
  u16* wqb  = xb + SZ_X;
  u16* wpb  = wqb + SZ_WQ;
  u16* qb   = wpb + SZ_WP;
  u16* kb   = qb + SZ_HED;
  u16* vtb  = kb + SZ_HED;     // V transposed, sigma-permuted [bh][d][n']
  u16* attn = vtb + SZ_HED;

  const int n0 = (int)(SZ_X / 4), n1 = (int)(SZ_WQ / 4), n2 = (int)(SZ_WP / 4);
  const int nblk = (n0 + n1 + n2 + 255) / 256;
  cvt_bf16_3<<<nblk, 256, 0, stream>>>(x, xb, n0, w_qkv, wqb, n1, w_proj, wpb, n2);

  gemm_bt<0><<<dim3(128, 18), 256, 0, stream>>>(xb, wqb, qb, kb, vtb, nullptr, nullptr);
  flash_attn<<<1536, 256, 0, stream>>>(qb, kb, vtb, attn);
  gemm_bt<1><<<dim3(128, 6), 256, 0, stream>>>(attn, wpb, nullptr, nullptr, nullptr,
                                               (float*)d_out, b_proj);
}

// Round 10
// 251.678 us; speedup vs baseline: 1.2217x; 1.0450x over previous
//
#include <hip/hip_runtime.h>
#include <stdint.h>

// StandardAttention: B=16, N=1024, DIM=768, H=12, Dh=64, SCALE=0.125
// FINAL (r7-best replica, 259.8us measured):
// fused cvt(x,w_qkv,w_proj) -> gemm_qkv (128^2 m97-structure, 3+ blocks/CU)
// -> flash_attn (S^T form, 2^x, no online max; in-register P; Q=32 rows/wave;
//    XCD-swizzled 1D grid; K+V in LDS; l via MFMA-ones)
// -> gemm_proj (same 128^2 structure, +bias fp32).
// Session ledger (what was tried, what stuck):
// r1/r2: 256^2 8-phase rewrite = 137us vs 87us (576 blocks @1/CU = 2.25
//   serialized passes; 2-wave/SIMD lockstep). Dead end at this shape.
// r3: fused cvt x3 -> 1 launch (+); setprio around MFMA clusters (+).
// r4 WIN: in-register P. sigma(n)=((n>>2)&3)*8+((n>>4)&1)*4+(n&3) permutes
//   P-cols and V-rows identically (key axis private to attention); the lane's
//   packed S^T regs ARE the PV A-fragment. V^T written sigma-permuted in
//   gemm_qkv epilogue (8B stores). Flash LDS bounce removed; QKV 83->66us.
// r5/r6 FAILURE: Q=64 rows/wave spills (WRITE 425/160MB vs 25MB algo).
//   Q=32/wave fits. Do not raise rows/wave.
// r6 WIN: XCD-bijective swizzle (bid -> bh=x+8c, qt): same-bh blocks
//   congruent mod 8 -> same XCD L2; flash FETCH at compulsory min (76.5MB).
// r8 FAILURE: V direct-from-L2 (no LDS) = 111.6us (scattered 64B segments +
//   exposed L2 latency beat the LDS-BW savings). V stays in LDS.
// r8 AUDIT: total - sum(kernels) ~= 90us fixed harness overhead, invariant
//   to launch count. Fusion is not a lever.
// r9: l via VALU instead of MFMA-ones = neutral (l-MFMAs were free).
// Structure ceilings (measured): cvt 14 (HBM roofline), qkv 68 (853TF ~
//   m97 ceiling), flash ~62 (serial-chain bound), proj 27 (743TF + 48MB
//   fp32 write). Occupancy already LDS-capped at 5 blocks/CU (VGPR 64/80).

typedef unsigned short u16;
typedef __attribute__((ext_vector_type(8))) short s16x8;   // 8 x bf16 MFMA frag
typedef __attribute__((ext_vector_type(4))) float f32x4;   // MFMA accum
typedef __attribute__((ext_vector_type(4))) unsigned short u16x4;

#define SEQ 1024
#define NHEAD 12
#define HD 64

__device__ __forceinline__ u16 f2bf(float f) {
  union { float f; uint32_t u; } v; v.f = f;
  uint32_t u = v.u;
  return (u16)((u + 0x7FFFu + ((u >> 16) & 1u)) >> 16);   // RNE
}

__device__ __forceinline__ float exp2_fast(float x) {
  return __builtin_amdgcn_exp2f(x);
}

__device__ __forceinline__ uint32_t pk_bf16(float a, float b) {
#if __has_builtin(__builtin_amdgcn_cvt_pk_bf16_f32)
  typedef __attribute__((ext_vector_type(2))) __bf16 bf2;
  union { bf2 v; uint32_t u; } c;
  c.v = __builtin_amdgcn_cvt_pk_bf16_f32(a, b);
  return c.u;
#else
  union { float f; uint32_t u; } ua, ub; ua.f = a; ub.f = b;
  const uint32_t ra = ua.u + 0x8000u, rb = ub.u + 0x8000u;
  return __builtin_amdgcn_perm(ra, rb, 0x03020706u);
#endif
}

__device__ __forceinline__ void gld_lds16(const void* g, void* l) {
  __builtin_amdgcn_global_load_lds((const __attribute__((address_space(1))) void*)g,
                                   (__attribute__((address_space(3))) void*)l, 16, 0, 0);
}

// One launch converts x, w_qkv, w_proj (3 disjoint fp32 sources -> contiguous
// bf16 workspace regions). Block-range select; branches are wave-uniform
// except at the two boundaries.
__global__ void cvt_bf16_3(const float* __restrict__ in0, u16* __restrict__ out0, int n0,
                           const float* __restrict__ in1, u16* __restrict__ out1, int n1,
                           const float* __restrict__ in2, u16* __restrict__ out2, int n2) {
  int i = blockIdx.x * blockDim.x + threadIdx.x;
  const float* in; u16* out;
  if (i < n0)            { in = in0; out = out0; }
  else if (i < n0 + n1)  { in = in1; out = out1; i -= n0; }
  else if (i < n0 + n1 + n2) { in = in2; out = out2; i -= n0 + n1; }
  else return;
  float4 f = ((const float4*)in)[i];
  u16x4 o;
  o.x = f2bf(f.x); o.y = f2bf(f.y); o.z = f2bf(f.z); o.w = f2bf(f.w);
  ((u16x4*)out)[i] = o;
}

// C = A[M,768] @ B^T, B row-major [N,768]. 128x128 tile, BK=64, 3 blocks/CU.
// EPI=0: scatter q(*0.125*log2e)/k to [B,H,N,64], V TRANSPOSED+sigma-permuted
//        to [B,H,64,N'] (N' = key-permuted column order for flash's in-reg P).
// EPI=1: +bias, fp32 out.
template <int EPI>
__global__ __launch_bounds__(256, 3)
void gemm_bt(const u16* __restrict__ A, const u16* __restrict__ B,
             u16* __restrict__ q, u16* __restrict__ k, u16* __restrict__ v,
             float* __restrict__ out, const float* __restrict__ bias) {
  __shared__ u16 As[128 * 64];
  __shared__ u16 Bs[128 * 64];
  const int tid = threadIdx.x;
  const int wv = tid >> 6, lane = tid & 63;
  const int quad = lane >> 4, l16 = lane & 15;
  const int m0 = blockIdx.x * 128, n0 = blockIdx.y * 128;
  const int wm = (wv & 1) * 64, wn = (wv >> 1) * 64;

  f32x4 acc[4][4];
#pragma unroll
  for (int i = 0; i < 4; i++)
#pragma unroll
    for (int j = 0; j < 4; j++) { acc[i][j].x = 0.f; acc[i][j].y = 0.f; acc[i][j].z = 0.f; acc[i][j].w = 0.f; }

  const int srow = (lane >> 3);
  const int scp = lane & 7;

  for (int kt = 0; kt < 768; kt += 64) {
    __syncthreads();
#pragma unroll
    for (int i = 0; i < 4; i++) {
      const int t = wv * 4 + i;
      const int row = t * 8 + srow;
      const int c = scp ^ (row & 7);
      gld_lds16(A + (size_t)(m0 + row) * 768 + kt + c * 8, &As[t * 512]);
      gld_lds16(B + (size_t)(n0 + row) * 768 + kt + c * 8, &Bs[t * 512]);
    }
    __syncthreads();
#pragma unroll
    for (int ks = 0; ks < 2; ks++) {
      s16x8 af[4], bf[4];
#pragma unroll
      for (int mi = 0; mi < 4; mi++) {
        const int ra = wm + mi * 16 + l16;
        const int ca = ((ks * 4 + quad) ^ (ra & 7)) * 8;
        af[mi] = *(const s16x8*)&As[ra * 64 + ca];
        const int rb = wn + mi * 16 + l16;
        const int cb = ((ks * 4 + quad) ^ (rb & 7)) * 8;
        bf[mi] = *(const s16x8*)&Bs[rb * 64 + cb];
      }
#pragma unroll
      for (int mi = 0; mi < 4; mi++)
#pragma unroll
        for (int ni = 0; ni < 4; ni++)
          acc[mi][ni] = __builtin_amdgcn_mfma_f32_16x16x32_bf16(af[mi], bf[ni], acc[mi][ni], 0, 0, 0);
    }
  }

  if (EPI == 0) {
#pragma unroll
    for (int ni = 0; ni < 4; ni++) {
      const int n = n0 + wn + ni * 16 + l16;
      const int which = n / 768;          // uniform per block (n-range within one third)
      const int rc = n % 768;
      const int head = rc >> 6, d = rc & 63;
      if (which == 2) {
        // V: transposed + sigma-permuted columns; r=0..3 stay contiguous -> 8B store
#pragma unroll
        for (int mi = 0; mi < 4; mi++) {
          const int mb = m0 + wm + mi * 16 + quad * 4;   // 4-aligned, same 1024-group for r=0..3
          const int b = mb >> 10, rrb = mb & 1023;
          const int vcol = (rrb & ~31) | (((rrb >> 2) & 3) << 3) | (((rrb >> 4) & 1) << 2);
          u16x4 pk4;
          pk4.x = f2bf(acc[mi][ni][0]); pk4.y = f2bf(acc[mi][ni][1]);
          pk4.z = f2bf(acc[mi][ni][2]); pk4.w = f2bf(acc[mi][ni][3]);
          *(u16x4*)&v[((size_t)(b * NHEAD + head) * HD + d) * SEQ + vcol] = pk4;
        }
      } else {
#pragma unroll
        for (int mi = 0; mi < 4; mi++) {
#pragma unroll
          for (int r = 0; r < 4; r++) {
            const int m = m0 + wm + mi * 16 + quad * 4 + r;
            const int b = m >> 10, rr = m & 1023;
            const float val = acc[mi][ni][r];
            if (which == 0)   // fold SCALE * log2(e) so flash uses 2^x directly
              q[((size_t)(b * NHEAD + head) * SEQ + rr) * HD + d] = f2bf(val * 0.18033688011112042f);
            else
              k[((size_t)(b * NHEAD + head) * SEQ + rr) * HD + d] = f2bf(val);
          }
        }
      }
    }
  } else {
#pragma unroll
    for (int mi = 0; mi < 4; mi++)
#pragma unroll
      for (int ni = 0; ni < 4; ni++)
#pragma unroll
        for (int r = 0; r < 4; r++) {
          const int m = m0 + wm + mi * 16 + quad * 4 + r;
          const int n = n0 + wn + ni * 16 + l16;
          out[(size_t)m * 768 + n] = acc[mi][ni][r] + bias[n];
        }
  }
}

// Flash attention, S^T form, no online max, 2^x. K and V double-buffered in
// LDS; in-register P (r4 sigma trick); l via MFMA-ones (overlapped, free —
// r9 showed removing them is neutral). Q=32 rows/wave.
// Grid: 1D 1536 with XCD-bijective swizzle (same-bh blocks share an XCD L2).
__global__ __launch_bounds__(256, 3)
void flash_attn(const u16* __restrict__ Q, const u16* __restrict__ K,
                const u16* __restrict__ VT, u16* __restrict__ O) {
  __shared__ u16 Ks[2][64 * 64];        // [key][d], chunks swizzled by key&7
  __shared__ u16 Vs[2][64 * 64];        // [d][key'], chunks swizzled by d&7

  const int tid = threadIdx.x;
  const int wv = tid >> 6, lane = tid & 63;
  const int quad = lane >> 4, l16 = lane & 15;
  // bid = 64c + 8q + x  ->  bh = x + 8c (0..191), qtile = q (0..7).
  // Same-bh blocks congruent mod 8 -> same XCD under round-robin dispatch.
  const int bid = blockIdx.x;
  const int bh = (bid & 7) + 8 * (bid >> 6);
  const int qt = (bid >> 3) & 7;
  const int q0 = qt * 128 + wv * 32;
  const size_t base = (size_t)bh * SEQ * HD;
  const size_t vbase = (size_t)bh * HD * SEQ;

  const int sr0 = tid >> 3;
  const int sc0 = (tid & 7) ^ (sr0 & 7);
  const int sr1 = 32 + sr0;
  const int sc1 = (tid & 7) ^ (sr1 & 7);

  s16x8 qf[2][2];
#pragma unroll
  for (int g = 0; g < 2; g++)
#pragma unroll
    for (int ks = 0; ks < 2; ks++)
      qf[g][ks] = *(const s16x8*)(Q + base + (size_t)(q0 + g * 16 + l16) * HD + ks * 32 + quad * 8);

  const s16x8 ones = {0x3F80, 0x3F80, 0x3F80, 0x3F80, 0x3F80, 0x3F80, 0x3F80, 0x3F80};

  f32x4 acc[2][4], acc_l[2];
#pragma unroll
  for (int g = 0; g < 2; g++) {
    acc_l[g].x = 0.f; acc_l[g].y = 0.f; acc_l[g].z = 0.f; acc_l[g].w = 0.f;
#pragma unroll
    for (int t = 0; t < 4; t++) { acc[g][t].x = 0.f; acc[g][t].y = 0.f; acc[g][t].z = 0.f; acc[g][t].w = 0.f; }
  }

  const int swz = l16 & 7;

  gld_lds16(K + base + (size_t)sr0 * HD + sc0 * 8, &Ks[0][wv * 512]);
  gld_lds16(VT + vbase + (size_t)sr0 * SEQ + sc0 * 8, &Vs[0][wv * 512]);
  gld_lds16(K + base + (size_t)sr1 * HD + sc1 * 8, &Ks[0][2048 + wv * 512]);
  gld_lds16(VT + vbase + (size_t)sr1 * SEQ + sc1 * 8, &Vs[0][2048 + wv * 512]);

  for (int it = 0; it < 16; it++) {
    __syncthreads();
    if (it + 1 < 16) {
      const int n1 = (it + 1) * 64;
      const int nb = (it + 1) & 1;
      gld_lds16(K + base + (size_t)(n1 + sr0) * HD + sc0 * 8, &Ks[nb][wv * 512]);
      gld_lds16(VT + vbase + (size_t)sr0 * SEQ + n1 + sc0 * 8, &Vs[nb][wv * 512]);
      gld_lds16(K + base + (size_t)(n1 + sr1) * HD + sc1 * 8, &Ks[nb][2048 + wv * 512]);
      gld_lds16(VT + vbase + (size_t)sr1 * SEQ + n1 + sc1 * 8, &Vs[nb][2048 + wv * 512]);
    }
    const u16* __restrict__ ks = Ks[it & 1];
    const u16* __restrict__ vs = Vs[it & 1];

    // S^T = K Q^T (q pre-scaled by 0.125*log2e)
    f32x4 s0[4], s1[4];
    __builtin_amdgcn_s_setprio(1);
#pragma unroll
    for (int t = 0; t < 4; t++) {
      s0[t].x = 0.f; s0[t].y = 0.f; s0[t].z = 0.f; s0[t].w = 0.f;
      s1[t].x = 0.f; s1[t].y = 0.f; s1[t].z = 0.f; s1[t].w = 0.f;
      const u16* kr = &ks[(t * 16 + l16) * 64];
      const s16x8 kf0 = *(const s16x8*)&kr[(quad ^ swz) * 8];
      const s16x8 kf1 = *(const s16x8*)&kr[((4 + quad) ^ swz) * 8];
      s0[t] = __builtin_amdgcn_mfma_f32_16x16x32_bf16(kf0, qf[0][0], s0[t], 0, 0, 0);
      s0[t] = __builtin_amdgcn_mfma_f32_16x16x32_bf16(kf1, qf[0][1], s0[t], 0, 0, 0);
      s1[t] = __builtin_amdgcn_mfma_f32_16x16x32_bf16(kf0, qf[1][0], s1[t], 0, 0, 0);
      s1[t] = __builtin_amdgcn_mfma_f32_16x16x32_bf16(kf1, qf[1][1], s1[t], 0, 0, 0);
    }
    __builtin_amdgcn_s_setprio(0);

    // p = 2^s
#pragma unroll
    for (int t = 0; t < 4; t++)
#pragma unroll
      for (int r = 0; r < 4; r++) {
        s0[t][r] = exp2_fast(s0[t][r]);
        s1[t][r] = exp2_fast(s1[t][r]);
      }

    // O += P V ; l += P @ ones. A-frags built in-register: slot quad*8+j holds
    // key 32*ks2 + quad*4 + 16*(j>>2) + (j&3) = exactly s[2*ks2 + (j>>2)][j&3];
    // sigma-permuted Vs columns supply the matching keys.
    __builtin_amdgcn_s_setprio(1);
#pragma unroll
    for (int ks2 = 0; ks2 < 2; ks2++) {
      union { uint32_t w[4]; s16x8 v; } pa0, pa1;
      pa0.w[0] = pk_bf16(s0[2 * ks2][0], s0[2 * ks2][1]);
      pa0.w[1] = pk_bf16(s0[2 * ks2][2], s0[2 * ks2][3]);
      pa0.w[2] = pk_bf16(s0[2 * ks2 + 1][0], s0[2 * ks2 + 1][1]);
      pa0.w[3] = pk_bf16(s0[2 * ks2 + 1][2], s0[2 * ks2 + 1][3]);
      pa1.w[0] = pk_bf16(s1[2 * ks2][0], s1[2 * ks2][1]);
      pa1.w[1] = pk_bf16(s1[2 * ks2][2], s1[2 * ks2][3]);
      pa1.w[2] = pk_bf16(s1[2 * ks2 + 1][0], s1[2 * ks2 + 1][1]);
      pa1.w[3] = pk_bf16(s1[2 * ks2 + 1][2], s1[2 * ks2 + 1][3]);
      acc_l[0] = __builtin_amdgcn_mfma_f32_16x16x32_bf16(pa0.v, ones, acc_l[0], 0, 0, 0);
      acc_l[1] = __builtin_amdgcn_mfma_f32_16x16x32_bf16(pa1.v, ones, acc_l[1], 0, 0, 0);
      const int cp = ((ks2 * 4 + quad) ^ swz) * 8;
#pragma unroll
      for (int t2 = 0; t2 < 4; t2++) {
        const s16x8 vf = *(const s16x8*)&vs[(t2 * 16 + l16) * 64 + cp];
        acc[0][t2] = __builtin_amdgcn_mfma_f32_16x16x32_bf16(pa0.v, vf, acc[0][t2], 0, 0, 0);
        acc[1][t2] = __builtin_amdgcn_mfma_f32_16x16x32_bf16(pa1.v, vf, acc[1][t2], 0, 0, 0);
      }
    }
    __builtin_amdgcn_s_setprio(0);
  }

  // write attn_out bf16 [B, N, H*64]; acc_l rows coincide with acc rows
  const int b = bh / NHEAD, h = bh % NHEAD;
#pragma unroll
  for (int g = 0; g < 2; g++) {
#pragma unroll
    for (int r = 0; r < 4; r++) {
      const float li = 1.0f / acc_l[g][r];
      const int qrow = q0 + g * 16 + quad * 4 + r;
      u16* op = O + (size_t)(b * SEQ + qrow) * 768 + h * HD;
#pragma unroll
      for (int t2 = 0; t2 < 4; t2++)
        op[t2 * 16 + l16] = f2bf(acc[g][t2][r] * li);
    }
  }
}

extern "C" void kernel_launch(void* const* d_in, const int* in_sizes, int n_in,
                              void* d_out, int out_size, void* d_ws, size_t ws_size,
                              hipStream_t stream) {
  (void)in_sizes; (void)n_in; (void)out_size; (void)ws_size;
  const float* x      = (const float*)d_in[0];
  const float* w_qkv  = (const float*)d_in[1];
  const float* w_proj = (const float*)d_in[2];
  const float* b_proj = (const float*)d_in[3];

  const size_t SZ_X   = (size_t)16384 * 768;
  const size_t SZ_WQ  = (size_t)2304 * 768;
  const size_t SZ_WP  = (size_t)768 * 768;
  const size_t SZ_HED = (size_t)16 * NHEAD * SEQ * HD;

  u16* xb   = (u16*)d_ws;
  u16* wqb  = xb + SZ_X;
  u16* wpb  = wqb + SZ_WQ;
  u16* qb   = wpb + SZ_WP;
  u16* kb   = qb + SZ_HED;
  u16* vtb  = kb + SZ_HED;     // V transposed, sigma-permuted [bh][d][n']
  u16* attn = vtb + SZ_HED;

  const int n0 = (int)(SZ_X / 4), n1 = (int)(SZ_WQ / 4), n2 = (int)(SZ_WP / 4);
  const int nblk = (n0 + n1 + n2 + 255) / 256;
  cvt_bf16_3<<<nblk, 256, 0, stream>>>(x, xb, n0, w_qkv, wqb, n1, w_proj, wpb, n2);

  gemm_bt<0><<<dim3(128, 18), 256, 0, stream>>>(xb, wqb, qb, kb, vtb, nullptr, nullptr);
  flash_attn<<<1536, 256, 0, stream>>>(qb, kb, vtb, attn);
  gemm_bt<1><<<dim3(128, 6), 256, 0, stream>>>(attn, wpb, nullptr, nullptr, nullptr,
                                               (float*)d_out, b_proj);
}